// Round 1
// baseline (315.695 us; speedup 1.0000x reference)
//
#include <hip/hip_runtime.h>
#include <stdint.h>

// ---------------------------------------------------------------------------
// TSA block: out = x + softmax((h Wq)(h Wk)^T / 32) (h Wv),  h = x + pos_enc
// B=4, S=2048, D=1024. fp32 I/O, f16 MFMA internals (threshold is bf16-floor).
// ---------------------------------------------------------------------------

#define AS1(p) ((__attribute__((address_space(1))) void*)(p))
#define AS3(p) ((__attribute__((address_space(3))) void*)(p))

typedef _Float16 f16x8 __attribute__((ext_vector_type(8)));
typedef _Float16 f16x4 __attribute__((ext_vector_type(4)));
typedef float f32x4 __attribute__((ext_vector_type(4)));

// ---------------- h = x + pe, cast to f16 ----------------------------------
__global__ __launch_bounds__(256) void make_h(const float* __restrict__ x,
                                              _Float16* __restrict__ h) {
  const size_t gid = (size_t)blockIdx.x * 256 + threadIdx.x;
  const size_t e = gid * 4;               // 4 consecutive d per thread
  const int d = (int)(e & 1023);
  const int m = (int)(e >> 10);
  const int s = m & 2047;                 // position within sequence
  const float4 xv = *(const float4*)(x + e);
  const int half = d >> 9;                // 0: sin block, 1: cos block
  const int j0 = d & 511;
  const float c = -0.017988946039016f;    // -ln(10000)/512
  float p[4];
#pragma unroll
  for (int t = 0; t < 4; t++) {
    const float r = __expf((float)(j0 + t) * c);
    const float a = (float)s * r;
    p[t] = half ? __cosf(a) : __sinf(a);
  }
  f16x4 o;
  o[0] = (_Float16)(xv.x + p[0]);
  o[1] = (_Float16)(xv.y + p[1]);
  o[2] = (_Float16)(xv.z + p[2]);
  o[3] = (_Float16)(xv.w + p[3]);
  *(f16x4*)(h + e) = o;
}

// ---------------- Wt[z][n][k] = (f16) W_z[k][n] ----------------------------
__global__ __launch_bounds__(256) void transpose_w(const float* __restrict__ Wq,
                                                   const float* __restrict__ Wk,
                                                   const float* __restrict__ Wv,
                                                   _Float16* __restrict__ Wt) {
  __shared__ float t[32][33];
  const int z = blockIdx.z;
  const float* W = (z == 0) ? Wq : (z == 1) ? Wk : Wv;
  _Float16* o = Wt + (size_t)z * 1024 * 1024;
  const int tx = threadIdx.x, ty = threadIdx.y;
  const int n0 = blockIdx.x * 32, k0 = blockIdx.y * 32;
#pragma unroll
  for (int i = ty; i < 32; i += 8)
    t[i][tx] = W[(size_t)(k0 + i) * 1024 + (n0 + tx)];
  __syncthreads();
#pragma unroll
  for (int i = ty; i < 32; i += 8)
    o[(size_t)(n0 + i) * 1024 + (k0 + tx)] = (_Float16)t[tx][i];
}

// ---------------- vT[b][d][j] = v[b][j][d] (f16) ---------------------------
__global__ __launch_bounds__(256) void transpose_v(const _Float16* __restrict__ v,
                                                   _Float16* __restrict__ vT) {
  __shared__ _Float16 t[32][33];
  const int z = blockIdx.z;
  const _Float16* in = v + (size_t)z * 2048 * 1024;
  _Float16* out = vT + (size_t)z * 1024 * 2048;
  const int tx = threadIdx.x, ty = threadIdx.y;
  const int d0 = blockIdx.x * 32, j0 = blockIdx.y * 32;
#pragma unroll
  for (int i = ty; i < 32; i += 8)
    t[i][tx] = in[(size_t)(j0 + i) * 1024 + (d0 + tx)];
  __syncthreads();
#pragma unroll
  for (int i = ty; i < 32; i += 8)
    out[(size_t)(d0 + i) * 2048 + (j0 + tx)] = t[tx][i];
}

// ---------------- row softmax: fp32 logits -> f16 attn ---------------------
__global__ __launch_bounds__(256) void softmax_rows(const float* __restrict__ L,
                                                    _Float16* __restrict__ P) {
  const size_t row = blockIdx.x;
  const float* lr = L + row * 2048;
  _Float16* pr = P + row * 2048;
  const int tid = threadIdx.x;
  const float4 v0 = *(const float4*)(lr + tid * 4);
  const float4 v1 = *(const float4*)(lr + 1024 + tid * 4);
  float mx = fmaxf(fmaxf(fmaxf(v0.x, v0.y), fmaxf(v0.z, v0.w)),
                   fmaxf(fmaxf(v1.x, v1.y), fmaxf(v1.z, v1.w)));
#pragma unroll
  for (int off = 32; off > 0; off >>= 1) mx = fmaxf(mx, __shfl_xor(mx, off));
  __shared__ float redm[4];
  __shared__ float reds[4];
  const int lane = tid & 63, wave = tid >> 6;
  if (lane == 0) redm[wave] = mx;
  __syncthreads();
  mx = fmaxf(fmaxf(redm[0], redm[1]), fmaxf(redm[2], redm[3]));
  float e[8];
  e[0] = __expf(v0.x - mx); e[1] = __expf(v0.y - mx);
  e[2] = __expf(v0.z - mx); e[3] = __expf(v0.w - mx);
  e[4] = __expf(v1.x - mx); e[5] = __expf(v1.y - mx);
  e[6] = __expf(v1.z - mx); e[7] = __expf(v1.w - mx);
  float sm = 0.f;
#pragma unroll
  for (int t = 0; t < 8; t++) sm += e[t];
#pragma unroll
  for (int off = 32; off > 0; off >>= 1) sm += __shfl_xor(sm, off);
  if (lane == 0) reds[wave] = sm;
  __syncthreads();
  sm = reds[0] + reds[1] + reds[2] + reds[3];
  const float inv = 1.0f / sm;
  f16x4 o0, o1;
  o0[0] = (_Float16)(e[0] * inv); o0[1] = (_Float16)(e[1] * inv);
  o0[2] = (_Float16)(e[2] * inv); o0[3] = (_Float16)(e[3] * inv);
  o1[0] = (_Float16)(e[4] * inv); o1[1] = (_Float16)(e[5] * inv);
  o1[2] = (_Float16)(e[6] * inv); o1[3] = (_Float16)(e[7] * inv);
  *(f16x4*)(pr + tid * 4) = o0;
  *(f16x4*)(pr + 1024 + tid * 4) = o1;
}

// ---------------- m97-style 128x128 A·B^T GEMM, f16 MFMA 16x16x32 ----------
// A: [M x K] row-major f16, Bt: [N x K] row-major f16 (i.e. B^T).
// MODE 0: C f16 [M x N] = A·B + bias(z)       (QKV projection)
// MODE 1: C f32 [M x N] = A·B * 1/32          (logits)
// MODE 2: C f32 [M x N] = A·B + X             (PV + residual)
template <int MODE>
__global__ __launch_bounds__(256) void gemm_bt(
    const _Float16* __restrict__ A0, long long sA,
    const _Float16* __restrict__ B0, long long sB,
    void* __restrict__ C0, long long sC,
    const float* __restrict__ aux0, const float* __restrict__ aux1,
    const float* __restrict__ aux2, long long sX,
    const int K, const int N) {
  __shared__ __align__(16) _Float16 As[128 * 32];
  __shared__ __align__(16) _Float16 Bs[128 * 32];
  const int tid = threadIdx.x;
  const int z = blockIdx.z;
  const int bm0 = blockIdx.x * 128, bn0 = blockIdx.y * 128;
  const _Float16* A = A0 + (size_t)z * sA;
  const _Float16* Bt = B0 + (size_t)z * sB;

  // staging pointers: thread t loads 16B from row (t>>2), col chunk (t&3)*8
  const _Float16* a0 = A + (size_t)(bm0 + (tid >> 2)) * K + (tid & 3) * 8;
  const _Float16* a1 = a0 + (size_t)64 * K;
  const _Float16* b0 = Bt + (size_t)(bn0 + (tid >> 2)) * K + (tid & 3) * 8;
  const _Float16* b1 = b0 + (size_t)64 * K;

  const int lane = tid & 63, wave = tid >> 6;
  const int wr = wave >> 1, wc = wave & 1;   // wave -> 64x64 quadrant
  const int quad = lane >> 4, l16 = lane & 15;

  f32x4 acc[4][4];
#pragma unroll
  for (int i = 0; i < 4; i++)
#pragma unroll
    for (int j = 0; j < 4; j++) {
      f32x4 zz = {0.f, 0.f, 0.f, 0.f};
      acc[i][j] = zz;
    }

  for (int k0 = 0; k0 < K; k0 += 32) {
    __syncthreads();  // protect LDS from previous iteration's readers
    __builtin_amdgcn_global_load_lds(AS1(a0 + k0), AS3(&As[tid * 8]), 16, 0, 0);
    __builtin_amdgcn_global_load_lds(AS1(a1 + k0), AS3(&As[tid * 8 + 2048]), 16, 0, 0);
    __builtin_amdgcn_global_load_lds(AS1(b0 + k0), AS3(&Bs[tid * 8]), 16, 0, 0);
    __builtin_amdgcn_global_load_lds(AS1(b1 + k0), AS3(&Bs[tid * 8 + 2048]), 16, 0, 0);
    __syncthreads();  // drains the global_load_lds queue
    f16x8 af[4], bfr[4];
#pragma unroll
    for (int i = 0; i < 4; i++)
      af[i] = *(const f16x8*)&As[(wr * 64 + i * 16 + l16) * 32 + quad * 8];
#pragma unroll
    for (int j = 0; j < 4; j++)
      bfr[j] = *(const f16x8*)&Bs[(wc * 64 + j * 16 + l16) * 32 + quad * 8];
#pragma unroll
    for (int i = 0; i < 4; i++)
#pragma unroll
      for (int j = 0; j < 4; j++)
        acc[i][j] = __builtin_amdgcn_mfma_f32_16x16x32_f16(af[i], bfr[j],
                                                           acc[i][j], 0, 0, 0);
  }

  // epilogue: C/D layout col = lane&15, row = quad*4 + reg
  const int rowb = bm0 + wr * 64 + quad * 4;
  const int colb = bn0 + wc * 64 + l16;
  if (MODE == 0) {
    _Float16* C = (_Float16*)C0 + (size_t)z * sC;
    const float* bias = (z == 0) ? aux0 : (z == 1) ? aux1 : aux2;
#pragma unroll
    for (int i = 0; i < 4; i++)
#pragma unroll
      for (int j = 0; j < 4; j++) {
        const int gn = colb + j * 16;
        const float bb = bias[gn];
#pragma unroll
        for (int r = 0; r < 4; r++)
          C[(size_t)(rowb + i * 16 + r) * N + gn] = (_Float16)(acc[i][j][r] + bb);
      }
  } else if (MODE == 1) {
    float* C = (float*)C0 + (size_t)z * sC;
#pragma unroll
    for (int i = 0; i < 4; i++)
#pragma unroll
      for (int j = 0; j < 4; j++)
#pragma unroll
        for (int r = 0; r < 4; r++)
          C[(size_t)(rowb + i * 16 + r) * N + (colb + j * 16)] =
              acc[i][j][r] * 0.03125f;
  } else {
    float* C = (float*)C0 + (size_t)z * sC;
    const float* X = aux0 + (size_t)z * sX;
#pragma unroll
    for (int i = 0; i < 4; i++)
#pragma unroll
      for (int j = 0; j < 4; j++)
#pragma unroll
        for (int r = 0; r < 4; r++) {
          const size_t idx = (size_t)(rowb + i * 16 + r) * N + (colb + j * 16);
          C[idx] = acc[i][j][r] + X[idx];
        }
  }
}

// ---------------------------------------------------------------------------
extern "C" void kernel_launch(void* const* d_in, const int* in_sizes, int n_in,
                              void* d_out, int out_size, void* d_ws, size_t ws_size,
                              hipStream_t stream) {
  (void)in_sizes; (void)n_in; (void)out_size; (void)ws_size;
  const float* x  = (const float*)d_in[0];
  const float* Wq = (const float*)d_in[1];
  const float* bq = (const float*)d_in[2];
  const float* Wk = (const float*)d_in[3];
  const float* bk = (const float*)d_in[4];
  const float* Wv = (const float*)d_in[5];
  const float* bv = (const float*)d_in[6];
  float* out = (float*)d_out;
  char* ws = (char*)d_ws;

  // workspace layout (bytes), with liveness-based overlap:
  //   [0, 16M)        h (f16)        -- dead after QKV gemm; reused for vT
  //   [16M, 22M)      Wt (f16 x3)    -- dead after QKV gemm
  //   [22M+, +48M)    qkv (f16)      -- q,k dead after logits gemm; reused for attn
  //   [70M+, +64M)    logits (f32)
  _Float16* h      = (_Float16*)(ws);
  _Float16* vT     = (_Float16*)(ws);                 // overlays h
  _Float16* Wt     = (_Float16*)(ws + 16777216);
  _Float16* qkv    = (_Float16*)(ws + 23068672);
  _Float16* attn   = (_Float16*)(ws + 23068672);      // overlays q,k
  float*    logits = (float*)   (ws + 73400320);

  const long long E = 8388608;  // elements per [8192 x 1024] f16 tensor

  transpose_w<<<dim3(32, 32, 3), dim3(32, 8), 0, stream>>>(Wq, Wk, Wv, Wt);
  make_h<<<8192, 256, 0, stream>>>(x, h);

  // QKV: [8192x1024] @ Wt_z -> qkv_z, f16 out + bias
  gemm_bt<0><<<dim3(64, 8, 3), 256, 0, stream>>>(
      h, 0LL, Wt, 1048576LL, qkv, E, bq, bk, bv, 0LL, 1024, 1024);

  // vT[b][d][j] = v[b][j][d]
  transpose_v<<<dim3(32, 64, 4), dim3(32, 8), 0, stream>>>(qkv + 2 * E, vT);

  // logits[b] = q_b @ k_b^T / 32, fp32
  gemm_bt<1><<<dim3(16, 16, 4), 256, 0, stream>>>(
      qkv, 2097152LL, qkv + E, 2097152LL, logits, 4194304LL,
      nullptr, nullptr, nullptr, 0LL, 1024, 2048);

  softmax_rows<<<8192, 256, 0, stream>>>(logits, attn);

  // out[b] = attn_b @ vT_b^T + x_b, fp32
  gemm_bt<2><<<dim3(16, 8, 4), 256, 0, stream>>>(
      attn, 4194304LL, vT, 2097152LL, out, 2097152LL,
      x, nullptr, nullptr, 2097152LL, 2048, 1024);
}

// Round 2
// 314.432 us; speedup vs baseline: 1.0040x; 1.0040x over previous
//
#include <hip/hip_runtime.h>
#include <stdint.h>

// ---------------------------------------------------------------------------
// TSA block: out = x + softmax((h Wq)(h Wk)^T / 32) (h Wv),  h = x + pos_enc
// B=4, S=2048, D=1024. fp32 I/O, f16 MFMA internals.
// R2: XOR-swizzled LDS staging (kill 4-way bank conflicts), f16 logits.
// ---------------------------------------------------------------------------

#define AS1(p) ((__attribute__((address_space(1))) void*)(p))
#define AS3(p) ((__attribute__((address_space(3))) void*)(p))

typedef _Float16 f16x8 __attribute__((ext_vector_type(8)));
typedef _Float16 f16x4 __attribute__((ext_vector_type(4)));
typedef float f32x4 __attribute__((ext_vector_type(4)));

// ---------------- h = x + pe, cast to f16 ----------------------------------
__global__ __launch_bounds__(256) void make_h(const float* __restrict__ x,
                                              _Float16* __restrict__ h) {
  const size_t gid = (size_t)blockIdx.x * 256 + threadIdx.x;
  const size_t e = gid * 4;               // 4 consecutive d per thread
  const int d = (int)(e & 1023);
  const int m = (int)(e >> 10);
  const int s = m & 2047;                 // position within sequence
  const float4 xv = *(const float4*)(x + e);
  const int half = d >> 9;                // 0: sin block, 1: cos block
  const int j0 = d & 511;
  const float c = -0.017988946039016f;    // -ln(10000)/512
  float p[4];
#pragma unroll
  for (int t = 0; t < 4; t++) {
    const float r = __expf((float)(j0 + t) * c);
    const float a = (float)s * r;
    p[t] = half ? __cosf(a) : __sinf(a);
  }
  f16x4 o;
  o[0] = (_Float16)(xv.x + p[0]);
  o[1] = (_Float16)(xv.y + p[1]);
  o[2] = (_Float16)(xv.z + p[2]);
  o[3] = (_Float16)(xv.w + p[3]);
  *(f16x4*)(h + e) = o;
}

// ---------------- Wt[z][n][k] = (f16) W_z[k][n] ----------------------------
__global__ __launch_bounds__(256) void transpose_w(const float* __restrict__ Wq,
                                                   const float* __restrict__ Wk,
                                                   const float* __restrict__ Wv,
                                                   _Float16* __restrict__ Wt) {
  __shared__ float t[32][33];
  const int z = blockIdx.z;
  const float* W = (z == 0) ? Wq : (z == 1) ? Wk : Wv;
  _Float16* o = Wt + (size_t)z * 1024 * 1024;
  const int tx = threadIdx.x, ty = threadIdx.y;
  const int n0 = blockIdx.x * 32, k0 = blockIdx.y * 32;
#pragma unroll
  for (int i = ty; i < 32; i += 8)
    t[i][tx] = W[(size_t)(k0 + i) * 1024 + (n0 + tx)];
  __syncthreads();
#pragma unroll
  for (int i = ty; i < 32; i += 8)
    o[(size_t)(n0 + i) * 1024 + (k0 + tx)] = (_Float16)t[tx][i];
}

// ---------------- vT[b][d][j] = v[b][j][d] (f16) ---------------------------
__global__ __launch_bounds__(256) void transpose_v(const _Float16* __restrict__ v,
                                                   _Float16* __restrict__ vT) {
  __shared__ _Float16 t[32][33];
  const int z = blockIdx.z;
  const _Float16* in = v + (size_t)z * 2048 * 1024;
  _Float16* out = vT + (size_t)z * 1024 * 2048;
  const int tx = threadIdx.x, ty = threadIdx.y;
  const int d0 = blockIdx.x * 32, j0 = blockIdx.y * 32;
#pragma unroll
  for (int i = ty; i < 32; i += 8)
    t[i][tx] = in[(size_t)(j0 + i) * 1024 + (d0 + tx)];
  __syncthreads();
#pragma unroll
  for (int i = ty; i < 32; i += 8)
    out[(size_t)(d0 + i) * 2048 + (j0 + tx)] = t[tx][i];
}

// ---------------- row softmax: f16 logits -> f16 attn ----------------------
__global__ __launch_bounds__(256) void softmax_rows(const _Float16* __restrict__ L,
                                                    _Float16* __restrict__ P) {
  const size_t row = blockIdx.x;
  const _Float16* lr = L + row * 2048;
  _Float16* pr = P + row * 2048;
  const int tid = threadIdx.x;
  const f16x8 v = *(const f16x8*)(lr + tid * 8);
  float f[8];
#pragma unroll
  for (int t = 0; t < 8; t++) f[t] = (float)v[t];
  float mx = f[0];
#pragma unroll
  for (int t = 1; t < 8; t++) mx = fmaxf(mx, f[t]);
#pragma unroll
  for (int off = 32; off > 0; off >>= 1) mx = fmaxf(mx, __shfl_xor(mx, off));
  __shared__ float redm[4];
  __shared__ float reds[4];
  const int lane = tid & 63, wave = tid >> 6;
  if (lane == 0) redm[wave] = mx;
  __syncthreads();
  mx = fmaxf(fmaxf(redm[0], redm[1]), fmaxf(redm[2], redm[3]));
  float e[8];
  float sm = 0.f;
#pragma unroll
  for (int t = 0; t < 8; t++) { e[t] = __expf(f[t] - mx); sm += e[t]; }
#pragma unroll
  for (int off = 32; off > 0; off >>= 1) sm += __shfl_xor(sm, off);
  if (lane == 0) reds[wave] = sm;
  __syncthreads();
  sm = reds[0] + reds[1] + reds[2] + reds[3];
  const float inv = 1.0f / sm;
  f16x8 o;
#pragma unroll
  for (int t = 0; t < 8; t++) o[t] = (_Float16)(e[t] * inv);
  *(f16x8*)(pr + tid * 8) = o;
}

// ---------------- m97-style 128x128 A·B^T GEMM, f16 MFMA 16x16x32 ----------
// A: [M x K] row-major f16, Bt: [N x K] row-major f16 (i.e. B^T).
// MODE 0: C f16 [M x N] = A·B + bias(z)       (QKV projection)
// MODE 1: C f16 [M x N] = A·B * 1/32          (logits)
// MODE 2: C f32 [M x N] = A·B + X             (PV + residual)
// LDS layout is XOR-swizzled: row r, physical 8-elem chunk slot p holds
// logical chunk p ^ ((r>>2)&3). Staging swizzles the SOURCE (dest must stay
// lane-contiguous for global_load_lds); readers un-swizzle. Max bank
// aliasing drops 4-way -> 2-way (free per m136).
template <int MODE>
__global__ __launch_bounds__(256) void gemm_bt(
    const _Float16* __restrict__ A0, long long sA,
    const _Float16* __restrict__ B0, long long sB,
    void* __restrict__ C0, long long sC,
    const float* __restrict__ aux0, const float* __restrict__ aux1,
    const float* __restrict__ aux2, long long sX,
    const int K, const int N) {
  __shared__ __align__(16) _Float16 As[128 * 32];
  __shared__ __align__(16) _Float16 Bs[128 * 32];
  const int tid = threadIdx.x;
  const int z = blockIdx.z;
  const int bm0 = blockIdx.x * 128, bn0 = blockIdx.y * 128;
  const _Float16* A = A0 + (size_t)z * sA;
  const _Float16* Bt = B0 + (size_t)z * sB;

  // staging: thread t -> row (t>>2), SOURCE chunk (t&3)^((t>>4)&3), dest slot (t&3)
  const int srow = tid >> 2;
  const int csrc = (tid & 3) ^ ((tid >> 4) & 3);
  const _Float16* a0 = A + (size_t)(bm0 + srow) * K + csrc * 8;
  const _Float16* a1 = a0 + (size_t)64 * K;   // srow+64: (r>>2)&3 unchanged
  const _Float16* b0 = Bt + (size_t)(bn0 + srow) * K + csrc * 8;
  const _Float16* b1 = b0 + (size_t)64 * K;

  const int lane = tid & 63, wave = tid >> 6;
  const int wr = wave >> 1, wc = wave & 1;   // wave -> 64x64 quadrant
  const int quad = lane >> 4, l16 = lane & 15;
  const int cq = (quad ^ ((l16 >> 2) & 3)) * 8;  // un-swizzled chunk offset

  f32x4 acc[4][4];
#pragma unroll
  for (int i = 0; i < 4; i++)
#pragma unroll
    for (int j = 0; j < 4; j++) {
      f32x4 zz = {0.f, 0.f, 0.f, 0.f};
      acc[i][j] = zz;
    }

  for (int k0 = 0; k0 < K; k0 += 32) {
    __syncthreads();  // protect LDS from previous iteration's readers
    __builtin_amdgcn_global_load_lds(AS1(a0 + k0), AS3(&As[tid * 8]), 16, 0, 0);
    __builtin_amdgcn_global_load_lds(AS1(a1 + k0), AS3(&As[tid * 8 + 2048]), 16, 0, 0);
    __builtin_amdgcn_global_load_lds(AS1(b0 + k0), AS3(&Bs[tid * 8]), 16, 0, 0);
    __builtin_amdgcn_global_load_lds(AS1(b1 + k0), AS3(&Bs[tid * 8 + 2048]), 16, 0, 0);
    __syncthreads();  // drains the global_load_lds queue
    f16x8 af[4], bfr[4];
#pragma unroll
    for (int i = 0; i < 4; i++)
      af[i] = *(const f16x8*)&As[(wr * 64 + i * 16 + l16) * 32 + cq];
#pragma unroll
    for (int j = 0; j < 4; j++)
      bfr[j] = *(const f16x8*)&Bs[(wc * 64 + j * 16 + l16) * 32 + cq];
#pragma unroll
    for (int i = 0; i < 4; i++)
#pragma unroll
      for (int j = 0; j < 4; j++)
        acc[i][j] = __builtin_amdgcn_mfma_f32_16x16x32_f16(af[i], bfr[j],
                                                           acc[i][j], 0, 0, 0);
  }

  // epilogue: C/D layout col = lane&15, row = quad*4 + reg
  const int rowb = bm0 + wr * 64 + quad * 4;
  const int colb = bn0 + wc * 64 + l16;
  if (MODE == 0 || MODE == 1) {
    _Float16* C = (_Float16*)C0 + (size_t)z * sC;
    const float* bias = (z == 0) ? aux0 : (z == 1) ? aux1 : aux2;
#pragma unroll
    for (int i = 0; i < 4; i++)
#pragma unroll
      for (int j = 0; j < 4; j++) {
        const int gn = colb + j * 16;
        const float bb = (MODE == 0) ? bias[gn] : 0.f;
#pragma unroll
        for (int r = 0; r < 4; r++) {
          const float val = (MODE == 0) ? (acc[i][j][r] + bb)
                                        : (acc[i][j][r] * 0.03125f);
          C[(size_t)(rowb + i * 16 + r) * N + gn] = (_Float16)val;
        }
      }
  } else {
    float* C = (float*)C0 + (size_t)z * sC;
    const float* X = aux0 + (size_t)z * sX;
#pragma unroll
    for (int i = 0; i < 4; i++)
#pragma unroll
      for (int j = 0; j < 4; j++)
#pragma unroll
        for (int r = 0; r < 4; r++) {
          const size_t idx = (size_t)(rowb + i * 16 + r) * N + (colb + j * 16);
          C[idx] = acc[i][j][r] + X[idx];
        }
  }
}

// ---------------------------------------------------------------------------
extern "C" void kernel_launch(void* const* d_in, const int* in_sizes, int n_in,
                              void* d_out, int out_size, void* d_ws, size_t ws_size,
                              hipStream_t stream) {
  (void)in_sizes; (void)n_in; (void)out_size; (void)ws_size;
  const float* x  = (const float*)d_in[0];
  const float* Wq = (const float*)d_in[1];
  const float* bq = (const float*)d_in[2];
  const float* Wk = (const float*)d_in[3];
  const float* bk = (const float*)d_in[4];
  const float* Wv = (const float*)d_in[5];
  const float* bv = (const float*)d_in[6];
  float* out = (float*)d_out;
  char* ws = (char*)d_ws;

  // workspace layout (bytes), with liveness-based overlap:
  //   [0, 16M)        h (f16)        -- dead after QKV gemm; reused for vT
  //   [16M, 22M)      Wt (f16 x3)    -- dead after QKV gemm
  //   [22M+, +48M)    qkv (f16)      -- q,k dead after logits gemm; reused for attn
  //   [70M+, +32M)    logits (f16)
  _Float16* h      = (_Float16*)(ws);
  _Float16* vT     = (_Float16*)(ws);                 // overlays h
  _Float16* Wt     = (_Float16*)(ws + 16777216);
  _Float16* qkv    = (_Float16*)(ws + 23068672);
  _Float16* attn   = (_Float16*)(ws + 23068672);      // overlays q,k
  _Float16* logits = (_Float16*)(ws + 73400320);

  const long long E = 8388608;  // elements per [8192 x 1024] f16 tensor

  transpose_w<<<dim3(32, 32, 3), dim3(32, 8), 0, stream>>>(Wq, Wk, Wv, Wt);
  make_h<<<8192, 256, 0, stream>>>(x, h);

  // QKV: [8192x1024] @ Wt_z -> qkv_z, f16 out + bias
  gemm_bt<0><<<dim3(64, 8, 3), 256, 0, stream>>>(
      h, 0LL, Wt, 1048576LL, qkv, E, bq, bk, bv, 0LL, 1024, 1024);

  // vT[b][d][j] = v[b][j][d]
  transpose_v<<<dim3(32, 64, 4), dim3(32, 8), 0, stream>>>(qkv + 2 * E, vT);

  // logits[b] = q_b @ k_b^T / 32, f16
  gemm_bt<1><<<dim3(16, 16, 4), 256, 0, stream>>>(
      qkv, 2097152LL, qkv + E, 2097152LL, logits, 4194304LL,
      nullptr, nullptr, nullptr, 0LL, 1024, 2048);

  softmax_rows<<<8192, 256, 0, stream>>>(logits, attn);

  // out[b] = attn_b @ vT_b^T + x_b, fp32
  gemm_bt<2><<<dim3(16, 8, 4), 256, 0, stream>>>(
      attn, 4194304LL, vT, 2097152LL, out, 2097152LL,
      x, nullptr, nullptr, 2097152LL, 2048, 1024);
}